// Round 2
// baseline (558.953 us; speedup 1.0000x reference)
//
#include <hip/hip_runtime.h>
#include <math.h>

// ContrastiveTokenLoss: B=2, T=2048, V=32000, ct_len=512, win=256.
// IGNORE_INDEX=-100, PAD_ID=0.
// loss[b,i] = log1p( sum_{j in [i-win, i), tgt[b,j]!=0} exp(x[b,i,tgt[b,j]] - x[b,i,tgt[b,i]]) )
// out = sum(loss * valid_tgt) / max(#valid_tgt, 1)
//
// R2 structure: one WAVE per row (4 rows / 256-thread block -> 256 blocks).
// Each lane owns 4 window positions -> 4 independent target->gather load
// chains in flight per wave (vs 1 in R1), no LDS, no __syncthreads.

#define IGNORE_INDEX (-100)
#define B_ 2
#define T_ 2048
#define V_ 32000
#define CT_LEN 512
#define WIN 256
#define NROWS (B_ * CT_LEN)

__global__ __launch_bounds__(256) void ctl_rows_kernel(
    const float* __restrict__ input,   // (B, T, V) fp32
    const int*   __restrict__ target,  // (B, T) int32
    float* __restrict__ loss_out,      // (NROWS,)
    float* __restrict__ valid_out)     // (NROWS,)
{
    const int wave = threadIdx.x >> 6;           // 0..3
    const int lane = threadIdx.x & 63;
    const int r = (blockIdx.x << 2) + wave;      // row id in [0, NROWS)
    const int b = r >> 9;                        // / CT_LEN
    const int i = r & (CT_LEN - 1);

    const int tgt_i = target[b * T_ + i];
    const bool valid = (tgt_i != IGNORE_INDEX);

    const float* row = input + ((size_t)b * T_ + (size_t)i) * (size_t)V_;
    const float pos = row[valid ? tgt_i : 0];    // broadcast load

    float s = 0.0f;
    if (valid) {
        #pragma unroll
        for (int c = 0; c < 4; ++c) {
            const int t = (c << 6) + lane;       // 0..255, coalesced per instr
            const int j = i - 1 - t;             // window position
            if (j >= 0) {
                const int tok = target[b * T_ + j];
                if (tok > 0 && tok < V_) {       // tok==0 is PAD
                    s += expf(row[tok] - pos);
                }
            }
        }
    }

    // wave-64 butterfly reduce
    #pragma unroll
    for (int off = 32; off > 0; off >>= 1)
        s += __shfl_down(s, off, 64);

    if (lane == 0) {
        loss_out[r]  = valid ? log1pf(s) : 0.0f;
        valid_out[r] = valid ? 1.0f : 0.0f;
    }
}

// Single-block final reduction over NROWS rows.
__global__ __launch_bounds__(256) void ctl_finalize_kernel(
    const float* __restrict__ loss,
    const float* __restrict__ valid,
    float* __restrict__ out)
{
    const int t = threadIdx.x;
    float ls = 0.0f, vs = 0.0f;
    #pragma unroll
    for (int k = 0; k < NROWS / 256; ++k) {
        ls += loss[k * 256 + t];
        vs += valid[k * 256 + t];
    }
    #pragma unroll
    for (int off = 32; off > 0; off >>= 1) {
        ls += __shfl_down(ls, off, 64);
        vs += __shfl_down(vs, off, 64);
    }
    __shared__ float sl[4], sv[4];
    const int lane = t & 63;
    const int wave = t >> 6;
    if (lane == 0) { sl[wave] = ls; sv[wave] = vs; }
    __syncthreads();
    if (t == 0) {
        const float L = sl[0] + sl[1] + sl[2] + sl[3];
        const float C = sv[0] + sv[1] + sv[2] + sv[3];
        const float denom = (C > 1.0f) ? C : 1.0f;
        out[0] = L / denom;
    }
}

extern "C" void kernel_launch(void* const* d_in, const int* in_sizes, int n_in,
                              void* d_out, int out_size, void* d_ws, size_t ws_size,
                              hipStream_t stream) {
    const float* input  = (const float*)d_in[0];   // (B,T,V) fp32
    const int*   target = (const int*)d_in[1];     // (B,T) int32
    float* out = (float*)d_out;

    float* loss_buf  = (float*)d_ws;               // NROWS floats
    float* valid_buf = loss_buf + NROWS;           // NROWS floats

    ctl_rows_kernel<<<NROWS / 4, 256, 0, stream>>>(input, target, loss_buf, valid_buf);
    ctl_finalize_kernel<<<1, 256, 0, stream>>>(loss_buf, valid_buf, out);
}